// Round 15
// baseline (63.186 us; speedup 1.0000x reference)
//
#include <hip/hip_runtime.h>

#define BN   8192
#define DIM  128
#define NCLS 128
#define NBLK 1024         // 32 col-blocks (256 cols) x 32 i-splits (256 rows)
#define NSTR 4            // strips of 64 rows per block

typedef __attribute__((ext_vector_type(8))) short bf16x8;   // 8 x bf16 = 4 VGPRs
typedef __attribute__((ext_vector_type(4))) float f32x4;

// round-to-nearest-even f32 -> bf16
static __device__ __forceinline__ unsigned short f2bf(float x) {
    union { float f; unsigned u; } c; c.f = x;
    unsigned r = c.u + 0x7FFFu + ((c.u >> 16) & 1u);
    return (unsigned short)(r >> 16);
}

static __device__ __forceinline__ bf16x8 ldb8(const unsigned short* p) {
    return *reinterpret_cast<const bf16x8*>(p);
}

// monotone float<->uint key: enc(a) < enc(b)  <=>  a < b
static __device__ __forceinline__ unsigned encf(float f) {
    unsigned u = __float_as_uint(f);
    return (u >> 31) ? ~u : (u | 0x80000000u);
}
static __device__ __forceinline__ float decf(unsigned v) {
    return __uint_as_float((v >> 31) ? (v & 0x7FFFFFFFu) : ~v);
}

// async global->LDS, 16B/lane; LDS dest wave-uniform base + lane*16
static __device__ __forceinline__ void gload_lds16(const unsigned short* g, unsigned short* l) {
    __builtin_amdgcn_global_load_lds(
        (const __attribute__((address_space(1))) unsigned int*)g,
        (__attribute__((address_space(3))) unsigned int*)l, 16, 0, 0);
}

// ------------- S1a: histogram + exclusive scan (ONE block, ~2us) ------------
// Replaces the O(NCLS*BN) per-class scans of the old 128-block sort_norm.
// Also (re)initializes the per-class scatter counters every call (graph-safe).
__global__ __launch_bounds__(1024) void hist_scan(const int* __restrict__ labels,
                                                  int* __restrict__ offs,
                                                  int* __restrict__ cnt) {
    __shared__ int h[NCLS];
    __shared__ int sc[NCLS];
    const int tid = threadIdx.x;
    if (tid < NCLS) h[tid] = 0;
    __syncthreads();
#pragma unroll
    for (int k = 0; k < BN / 1024; ++k) atomicAdd(&h[labels[k * 1024 + tid]], 1);
    __syncthreads();
    int x = 0;
    if (tid < NCLS) { x = h[tid]; sc[tid] = x; }
    __syncthreads();
    for (int off = 1; off < NCLS; off <<= 1) {       // Hillis-Steele inclusive
        int v = 0;
        if (tid < NCLS && tid >= off) v = sc[tid - off];
        __syncthreads();
        if (tid < NCLS) sc[tid] += v;
        __syncthreads();
    }
    if (tid < NCLS) { int e = sc[tid] - x; offs[tid] = e; cnt[tid] = e; }
    if (tid == 0) offs[NCLS] = BN;
}

// ------------- S1b: normalize + scatter (one wave per row, 2048 blocks) -----
// Rank within class via atomicAdd (R3 precedent): placement order is
// nondeterministic but every per-row quantity is placement-invariant, so the
// final min/max/loss values are unchanged.
__global__ __launch_bounds__(256) void norm_scatter(const float* __restrict__ emb,
                                                    const int* __restrict__ labels,
                                                    const int* __restrict__ offs,
                                                    int* __restrict__ cnt,
                                                    unsigned short* __restrict__ ebf,
                                                    int2* __restrict__ se,
                                                    unsigned* __restrict__ hp2,
                                                    unsigned* __restrict__ hn2) {
    const int row  = blockIdx.x * 4 + (threadIdx.x >> 6);
    const int lane = threadIdx.x & 63;
    float2 v = reinterpret_cast<const float2*>(emb + (size_t)row * DIM)[lane];
    float ss = v.x * v.x + v.y * v.y;
#pragma unroll
    for (int m = 1; m < 64; m <<= 1) ss += __shfl_xor(ss, m);
    float inv = 1.0f / fmaxf(sqrtf(ss), 1e-12f);
    int p = 0, c = 0;
    if (lane == 0) { c = labels[row]; p = atomicAdd(&cnt[c], 1); }
    p = __shfl(p, 0); c = __shfl(c, 0);
    ushort2 bv; bv.x = f2bf(v.x * inv); bv.y = f2bf(v.y * inv);
    reinterpret_cast<ushort2*>(ebf + (size_t)p * DIM)[lane] = bv;
    if (lane == 0) {
        se[p]  = make_int2(offs[c], offs[c + 1]);    // class range in sorted space
        hp2[p] = 0xFFFFFFFFu;                        // min-key identity
        hn2[p] = 0u;                                 // max-key identity
    }
}

// --------------------------------- main (byte-identical to passing R14) -----
// 1024 blocks = 32 col-blocks (256 cols) x 32 i-splits (256 rows, 4 strips).
// 64 cols/wave in regs (B=64 VGPR), LDS-staged A strips (double-buffered
// gload_lds + swizzle), hoisted pure-neg fast path. No fence, no done counter
// (R14: removing the per-block L2-flush storm was the big win).
__global__ __launch_bounds__(256) void tri_main(const unsigned short* __restrict__ ebf,
                                                const int2* __restrict__ se,
                                                unsigned* __restrict__ hp2,
                                                unsigned* __restrict__ hn2) {
    __shared__ alignas(16) unsigned short as_[2][64 * DIM];   // 2 x 16 KiB A strips

    const int tid  = threadIdx.x;
    const int wave = tid >> 6;
    const int lane = tid & 63;
    const int lr   = lane & 15;        // col within 16-subtile / A row in frag
    const int lk   = lane >> 4;        // k-group / C row-group
    const int jb   = blockIdx.x >> 5;  // col-block (256 cols)
    const int isp  = blockIdx.x & 31;  // i-split (256 rows)
    const int jc0  = jb * 256 + wave * 64;       // wave's col base (64 cols)
    const int rb0  = isp * 256;                  // block's row base

    // B fragments: 4 col-subtiles x 4 k-steps = 64 VGPRs, loaded once (L2-hit)
    bf16x8 b[4][4];
#pragma unroll
    for (int cs = 0; cs < 4; ++cs)
#pragma unroll
        for (int kk = 0; kk < 4; ++kk)
            b[cs][kk] = ldb8(ebf + (size_t)(jc0 + cs * 16 + lr) * DIM + kk * 32 + lk * 8);

    // lane's 4 columns' class ranges (loop-invariant)
    int qs[4], qe[4];
#pragma unroll
    for (int cs = 0; cs < 4; ++cs) {
        int2 q = se[jc0 + cs * 16 + lr];
        qs[cs] = q.x; qe[cs] = q.y;
    }

    float hp[4] = {1e30f, 1e30f, 1e30f, 1e30f};      // dot-space: min-pos
    float hn[4] = {-1e30f, -1e30f, -1e30f, -1e30f};  // dot-space: max-neg

    // A ds_read offsets: frag(t,kk) at byte (t*16+lr)*256 + perm[kk]
    int perm[4];
#pragma unroll
    for (int kk = 0; kk < 4; ++kk) perm[kk] = ((kk * 4 + lk) ^ (lr & 7)) << 4;

    // staging: wave stages rows [wave*16, wave*16+16) of the strip; source
    // chunk XOR'd by (row&7) so the linear LDS write realizes the swizzle
    const int rloc  = lane >> 4;             // row within 4-group
    const int chunk = lane & 15;             // physical 16B chunk
    auto STAGE = [&](int buf, int s) {
        const unsigned short* g0 = ebf + (size_t)(rb0 + s * 64) * DIM;
        unsigned short* lb = &as_[buf][wave * 16 * DIM];
#pragma unroll
        for (int l = 0; l < 4; ++l) {
            const int row = l * 4 + rloc;
            gload_lds16(g0 + (size_t)(wave * 16 + row) * DIM + ((chunk ^ (row & 7)) * 8),
                        lb + l * 4 * DIM);
        }
    };

    STAGE(0, 0);
    __syncthreads();

    for (int s = 0; s < NSTR; ++s) {
        if (s < NSTR - 1) STAGE((s + 1) & 1, s + 1);   // async prefetch next strip

        const char* bb = reinterpret_cast<const char*>(&as_[s & 1][0]);
        f32x4 acc[4][4];                     // [cs][t], unified VGPR/AGPR file
#pragma unroll
        for (int cs = 0; cs < 4; ++cs)
#pragma unroll
            for (int t = 0; t < 4; ++t) acc[cs][t] = f32x4{0.f, 0.f, 0.f, 0.f};

#pragma unroll
        for (int t = 0; t < 4; ++t)
#pragma unroll
            for (int kk = 0; kk < 4; ++kk) {
                bf16x8 af = *reinterpret_cast<const bf16x8*>(bb + (t * 16 + lr) * 256 + perm[kk]);
                acc[0][t] = __builtin_amdgcn_mfma_f32_16x16x32_bf16(af, b[0][kk], acc[0][t], 0, 0, 0);
                acc[1][t] = __builtin_amdgcn_mfma_f32_16x16x32_bf16(af, b[1][kk], acc[1][t], 0, 0, 0);
                acc[2][t] = __builtin_amdgcn_mfma_f32_16x16x32_bf16(af, b[2][kk], acc[2][t], 0, 0, 0);
                acc[3][t] = __builtin_amdgcn_mfma_f32_16x16x32_bf16(af, b[3][kk], acc[3][t], 0, 0, 0);
            }

        // epilogue: C layout col=lane&15, row=lk*4+m (+t*16)
        const int rb = rb0 + s * 64;
        bool mixed = false;
#pragma unroll
        for (int cs = 0; cs < 4; ++cs)
            mixed |= (qs[cs] < rb + 64) && (qe[cs] > rb);   // class range hits strip

        if (!__any(mixed)) {
            // pure-negative strip for every lane's columns: 1 fmax per element
#pragma unroll
            for (int cs = 0; cs < 4; ++cs) {
                float mx = hn[cs];
#pragma unroll
                for (int t = 0; t < 4; ++t)
#pragma unroll
                    for (int m = 0; m < 4; ++m) mx = fmaxf(mx, acc[cs][t][m]);
                hn[cs] = mx;
            }
        } else {                             // mixed strip (rare, near class band)
#pragma unroll
            for (int cs = 0; cs < 4; ++cs)
#pragma unroll
                for (int t = 0; t < 4; ++t)
#pragma unroll
                    for (int m = 0; m < 4; ++m) {
                        const int rowg = rb + t * 16 + lk * 4 + m;
                        const float d = acc[cs][t][m];
                        const bool pos = (rowg >= qs[cs]) && (rowg < qe[cs]);
                        hp[cs] = pos ? fminf(hp[cs], d) : hp[cs];
                        hn[cs] = pos ? hn[cs] : fmaxf(hn[cs], d);
                    }
        }

        __syncthreads();   // strip s reads done by all waves + strip s+1 landed
    }

    // combine the 4 lk-groups (lanes lr, lr+16, lr+32, lr+48 share columns)
#pragma unroll
    for (int cs = 0; cs < 4; ++cs) {
#pragma unroll
        for (int sft = 16; sft < 64; sft <<= 1) {
            hp[cs] = fminf(hp[cs], __shfl_xor(hp[cs], sft));
            hn[cs] = fmaxf(hn[cs], __shfl_xor(hn[cs], sft));
        }
    }
    if (lane < 16) {
#pragma unroll
        for (int cs = 0; cs < 4; ++cs) {
            atomicMin(&hp2[jc0 + cs * 16 + lane], encf(hp[cs]));
            atomicMax(&hn2[jc0 + cs * 16 + lane], encf(hn[cs]));
        }
    }
    // NO __threadfence, NO done counter: coherence from the kernel boundary.
}

// ---------------------------------------------------------------- finalize
__global__ __launch_bounds__(1024) void finalize_kernel(const unsigned* __restrict__ hp2,
                                                        const unsigned* __restrict__ hn2,
                                                        float* __restrict__ out) {
    const int tid = threadIdx.x;
    float sum = 0.f;
#pragma unroll
    for (int it = 0; it < BN / (1024 * 4); ++it) {   // 2 iters, uint4 per thread
        int base = (it * 1024 + tid) * 4;
        uint4 pv = *reinterpret_cast<const uint4*>(&hp2[base]);
        uint4 nv = *reinterpret_cast<const uint4*>(&hn2[base]);
        unsigned pa[4] = {pv.x, pv.y, pv.z, pv.w};
        unsigned na[4] = {nv.x, nv.y, nv.z, nv.w};
#pragma unroll
        for (int e = 0; e < 4; ++e) {
            float pd = decf(pa[e]);          // min dot over pos
            float nd = decf(na[e]);          // max dot over neg
            float hpv = sqrtf(fmaxf(2.0f - 2.0f * pd, 0.f));
            float hnv = sqrtf(fmaxf(2.0f - 2.0f * nd, 0.f));
            // relu(hp - hn + 0.5*(1+hp)) = relu(1.5*hp + 0.5 - hn)
            sum += fmaxf(fmaf(1.5f, hpv, 0.5f) - hnv, 0.f);
        }
    }
    __shared__ float red[1024];
    red[tid] = sum;
    __syncthreads();
    for (int s2 = 512; s2 > 0; s2 >>= 1) {
        if (tid < s2) red[tid] += red[tid + s2];
        __syncthreads();
    }
    if (tid == 0) out[0] = red[0] * (1.0f / (float)BN);    // all rows valid
}

// ---------------------------------------------------------------- launch
extern "C" void kernel_launch(void* const* d_in, const int* in_sizes, int n_in,
                              void* d_out, int out_size, void* d_ws, size_t ws_size,
                              hipStream_t stream) {
    const float* emb    = (const float*)d_in[0];
    const int*   labels = (const int*)d_in[1];
    float* out = (float*)d_out;

    char* ws = (char*)d_ws;
    unsigned short* ebf = (unsigned short*)ws;                            // 2 MiB sorted bf16 E
    int2*     se   = (int2*)    (ws + 2u * 1024u * 1024u);                // 64 KiB class ranges
    unsigned* hp2  = (unsigned*)(ws + 2u * 1024u * 1024u + 64u * 1024u);  // 32 KiB
    unsigned* hn2  = (unsigned*)(ws + 2u * 1024u * 1024u + 96u * 1024u);  // 32 KiB
    int*      offs = (int*)     (ws + 2u * 1024u * 1024u + 128u * 1024u); // 129 ints
    int*      cnt  = (int*)     (ws + 2u * 1024u * 1024u + 130u * 1024u); // 128 ints

    hipLaunchKernelGGL(hist_scan,       dim3(1),      dim3(1024), 0, stream, labels, offs, cnt);
    hipLaunchKernelGGL(norm_scatter,    dim3(BN / 4), dim3(256),  0, stream, emb, labels, offs, cnt, ebf, se, hp2, hn2);
    hipLaunchKernelGGL(tri_main,        dim3(NBLK),   dim3(256),  0, stream, ebf, se, hp2, hn2);
    hipLaunchKernelGGL(finalize_kernel, dim3(1),      dim3(1024), 0, stream, hp2, hn2, out);
}

// Round 16
// 61.888 us; speedup vs baseline: 1.0210x; 1.0210x over previous
//
#include <hip/hip_runtime.h>

#define BN   8192
#define DIM  128
#define NCLS 128
#define NBLK 2048         // 32 col-blocks (256 cols) x 64 i-splits (128 rows)
#define NSTR 2            // strips of 64 rows per block

typedef __attribute__((ext_vector_type(8))) short bf16x8;   // 8 x bf16 = 4 VGPRs
typedef __attribute__((ext_vector_type(4))) float f32x4;

// round-to-nearest-even f32 -> bf16
static __device__ __forceinline__ unsigned short f2bf(float x) {
    union { float f; unsigned u; } c; c.f = x;
    unsigned r = c.u + 0x7FFFu + ((c.u >> 16) & 1u);
    return (unsigned short)(r >> 16);
}

static __device__ __forceinline__ bf16x8 ldb8(const unsigned short* p) {
    return *reinterpret_cast<const bf16x8*>(p);
}

// monotone float<->uint key: enc(a) < enc(b)  <=>  a < b
static __device__ __forceinline__ unsigned encf(float f) {
    unsigned u = __float_as_uint(f);
    return (u >> 31) ? ~u : (u | 0x80000000u);
}
static __device__ __forceinline__ float decf(unsigned v) {
    return __uint_as_float((v >> 31) ? (v & 0x7FFFFFFFu) : ~v);
}

// async global->LDS, 16B/lane; LDS dest wave-uniform base + lane*16
static __device__ __forceinline__ void gload_lds16(const unsigned short* g, unsigned short* l) {
    __builtin_amdgcn_global_load_lds(
        (const __attribute__((address_space(1))) unsigned int*)g,
        (__attribute__((address_space(3))) unsigned int*)l, 16, 0, 0);
}

// ---------------- S1: fused sort (block-per-class) + normalize + init -------
// (R14 version, proven: the R15 hist_scan+norm_scatter split regressed -11us)
__global__ __launch_bounds__(256) void sort_norm(const float* __restrict__ emb,
                                                 const int* __restrict__ labels,
                                                 unsigned short* __restrict__ ebf,
                                                 int2* __restrict__ se,
                                                 unsigned* __restrict__ hp2,
                                                 unsigned* __restrict__ hn2) {
    const int c   = blockIdx.x;              // class id
    const int tid = threadIdx.x;
    __shared__ int slab[BN];                 // 32 KiB label cache
    __shared__ int sl[256], so[256];
    __shared__ int srcrow[512];              // class size guard (E=64, sd~8)

#pragma unroll 8
    for (int k = 0; k < 32; ++k) {           // one coalesced label pass
        int idx = k * 256 + tid;
        slab[idx] = labels[idx];
    }
    __syncthreads();

    int nl = 0, no = 0;
#pragma unroll 8
    for (int k = 0; k < 32; ++k) {
        int lb = slab[k * 256 + tid];
        nl += (lb < c);
        no += (lb == c);
    }
    sl[tid] = nl; so[tid] = no;
    __syncthreads();
    for (int off = 1; off < 256; off <<= 1) {   // Hillis-Steele inclusive scan
        int a1 = 0, a2 = 0;
        if (tid >= off) { a1 = sl[tid - off]; a2 = so[tid - off]; }
        __syncthreads();
        sl[tid] += a1; so[tid] += a2;
        __syncthreads();
    }
    const int offs_c = sl[255];              // rows with label < c
    const int n_c    = so[255];              // class size
    int mypos = so[tid] - no;                // exclusive prefix of own-count
    for (int k = 0; k < 32; ++k) {           // deterministic placement
        int r = k * 256 + tid;
        if (slab[r] == c) srcrow[mypos++] = r;
    }
    __syncthreads();

    const int wave = tid >> 6, lane = tid & 63;
    for (int k = wave; k < n_c; k += 4) {
        int r   = srcrow[k];
        int pos = offs_c + k;
        float2 v = reinterpret_cast<const float2*>(emb + (size_t)r * DIM)[lane];
        float ss = v.x * v.x + v.y * v.y;
#pragma unroll
        for (int m = 1; m < 64; m <<= 1) ss += __shfl_xor(ss, m);
        float inv = 1.0f / fmaxf(sqrtf(ss), 1e-12f);
        ushort2 bv; bv.x = f2bf(v.x * inv); bv.y = f2bf(v.y * inv);
        reinterpret_cast<ushort2*>(ebf + (size_t)pos * DIM)[lane] = bv;
        if (lane == 0) {
            se[pos]  = make_int2(offs_c, offs_c + n_c);
            hp2[pos] = 0xFFFFFFFFu;          // min-key identity
            hn2[pos] = 0u;                   // max-key identity
        }
    }
}

// --------------------------------- main -------------------------------------
// R14 structure (no fence, no done counter) with two conservative tweaks:
// (1) NSTR 4->2, NBLK 1024->2048: per-block barrier chain halved (3 barriers
//     vs 5), smaller blocks pack/tail better; B-prologue L2 traffic doubles
//     (~+3.7us aggregate) -- a good trade if the serial chain dominates.
// (2) sepk packing (start<<16|len): -4 VGPR, targeting the natural 128-VGPR
//     4-waves/SIMD tier WITHOUT launch-bounds coercion (R2/R9/R10 lesson).
__global__ __launch_bounds__(256) void tri_main(const unsigned short* __restrict__ ebf,
                                                const int2* __restrict__ se,
                                                unsigned* __restrict__ hp2,
                                                unsigned* __restrict__ hn2) {
    __shared__ alignas(16) unsigned short as_[2][64 * DIM];   // 2 x 16 KiB A strips

    const int tid  = threadIdx.x;
    const int wave = tid >> 6;
    const int lane = tid & 63;
    const int lr   = lane & 15;        // col within 16-subtile / A row in frag
    const int lk   = lane >> 4;        // k-group / C row-group
    const int jb   = blockIdx.x >> 6;  // col-block (256 cols), 0..31
    const int isp  = blockIdx.x & 63;  // i-split (128 rows), 0..63
    const int jc0  = jb * 256 + wave * 64;       // wave's col base (64 cols)
    const int rb0  = isp * 128;                  // block's row base

    // B fragments: 4 col-subtiles x 4 k-steps = 64 VGPRs, loaded once (L2-hit)
    bf16x8 b[4][4];
#pragma unroll
    for (int cs = 0; cs < 4; ++cs)
#pragma unroll
        for (int kk = 0; kk < 4; ++kk)
            b[cs][kk] = ldb8(ebf + (size_t)(jc0 + cs * 16 + lr) * DIM + kk * 32 + lk * 8);

    // lane's 4 columns' class ranges, packed (start<<16 | len): 4 regs not 8
    int sepk[4];
#pragma unroll
    for (int cs = 0; cs < 4; ++cs) {
        int2 q = se[jc0 + cs * 16 + lr];
        sepk[cs] = (q.x << 16) | (q.y - q.x);
    }

    float hp[4] = {1e30f, 1e30f, 1e30f, 1e30f};      // dot-space: min-pos
    float hn[4] = {-1e30f, -1e30f, -1e30f, -1e30f};  // dot-space: max-neg

    // A ds_read offsets: frag(t,kk) at byte (t*16+lr)*256 + perm[kk]
    int perm[4];
#pragma unroll
    for (int kk = 0; kk < 4; ++kk) perm[kk] = ((kk * 4 + lk) ^ (lr & 7)) << 4;

    // staging: wave stages rows [wave*16, wave*16+16) of the strip; source
    // chunk XOR'd by (row&7) so the linear LDS write realizes the swizzle
    const int rloc  = lane >> 4;             // row within 4-group
    const int chunk = lane & 15;             // physical 16B chunk
    auto STAGE = [&](int buf, int s) {
        const unsigned short* g0 = ebf + (size_t)(rb0 + s * 64) * DIM;
        unsigned short* lb = &as_[buf][wave * 16 * DIM];
#pragma unroll
        for (int l = 0; l < 4; ++l) {
            const int row = l * 4 + rloc;
            gload_lds16(g0 + (size_t)(wave * 16 + row) * DIM + ((chunk ^ (row & 7)) * 8),
                        lb + l * 4 * DIM);
        }
    };

    STAGE(0, 0);
    __syncthreads();

    for (int s = 0; s < NSTR; ++s) {
        if (s < NSTR - 1) STAGE((s + 1) & 1, s + 1);   // async prefetch next strip

        const char* bb = reinterpret_cast<const char*>(&as_[s & 1][0]);
        f32x4 acc[4][4];                     // [cs][t], unified VGPR/AGPR file
#pragma unroll
        for (int cs = 0; cs < 4; ++cs)
#pragma unroll
            for (int t = 0; t < 4; ++t) acc[cs][t] = f32x4{0.f, 0.f, 0.f, 0.f};

#pragma unroll
        for (int t = 0; t < 4; ++t)
#pragma unroll
            for (int kk = 0; kk < 4; ++kk) {
                bf16x8 af = *reinterpret_cast<const bf16x8*>(bb + (t * 16 + lr) * 256 + perm[kk]);
                acc[0][t] = __builtin_amdgcn_mfma_f32_16x16x32_bf16(af, b[0][kk], acc[0][t], 0, 0, 0);
                acc[1][t] = __builtin_amdgcn_mfma_f32_16x16x32_bf16(af, b[1][kk], acc[1][t], 0, 0, 0);
                acc[2][t] = __builtin_amdgcn_mfma_f32_16x16x32_bf16(af, b[2][kk], acc[2][t], 0, 0, 0);
                acc[3][t] = __builtin_amdgcn_mfma_f32_16x16x32_bf16(af, b[3][kk], acc[3][t], 0, 0, 0);
            }

        // epilogue: C layout col=lane&15, row=lk*4+m (+t*16)
        const int rb = rb0 + s * 64;
        bool mixed = false;
#pragma unroll
        for (int cs = 0; cs < 4; ++cs) {
            const int st  = sepk[cs] >> 16;
            const int len = sepk[cs] & 0xFFFF;
            mixed |= (st < rb + 64) && (st + len > rb);     // class range hits strip
        }

        if (!__any(mixed)) {
            // pure-negative strip for every lane's columns: 1 fmax per element
#pragma unroll
            for (int cs = 0; cs < 4; ++cs) {
                float mx = hn[cs];
#pragma unroll
                for (int t = 0; t < 4; ++t)
#pragma unroll
                    for (int m = 0; m < 4; ++m) mx = fmaxf(mx, acc[cs][t][m]);
                hn[cs] = mx;
            }
        } else {                             // mixed strip (rare, near class band)
#pragma unroll
            for (int cs = 0; cs < 4; ++cs) {
                const int st  = sepk[cs] >> 16;
                const int len = sepk[cs] & 0xFFFF;
#pragma unroll
                for (int t = 0; t < 4; ++t)
#pragma unroll
                    for (int m = 0; m < 4; ++m) {
                        const int rowg = rb + t * 16 + lk * 4 + m;
                        const float d = acc[cs][t][m];
                        const bool pos = (unsigned)(rowg - st) < (unsigned)len;
                        hp[cs] = pos ? fminf(hp[cs], d) : hp[cs];
                        hn[cs] = pos ? hn[cs] : fmaxf(hn[cs], d);
                    }
            }
        }

        __syncthreads();   // strip s reads done by all waves + strip s+1 landed
    }

    // combine the 4 lk-groups (lanes lr, lr+16, lr+32, lr+48 share columns)
#pragma unroll
    for (int cs = 0; cs < 4; ++cs) {
#pragma unroll
        for (int sft = 16; sft < 64; sft <<= 1) {
            hp[cs] = fminf(hp[cs], __shfl_xor(hp[cs], sft));
            hn[cs] = fmaxf(hn[cs], __shfl_xor(hn[cs], sft));
        }
    }
    if (lane < 16) {
#pragma unroll
        for (int cs = 0; cs < 4; ++cs) {
            atomicMin(&hp2[jc0 + cs * 16 + lane], encf(hp[cs]));
            atomicMax(&hn2[jc0 + cs * 16 + lane], encf(hn[cs]));
        }
    }
    // NO __threadfence, NO done counter: coherence from the kernel boundary.
}

// ---------------------------------------------------------------- finalize
__global__ __launch_bounds__(1024) void finalize_kernel(const unsigned* __restrict__ hp2,
                                                        const unsigned* __restrict__ hn2,
                                                        float* __restrict__ out) {
    const int tid = threadIdx.x;
    float sum = 0.f;
#pragma unroll
    for (int it = 0; it < BN / (1024 * 4); ++it) {   // 2 iters, uint4 per thread
        int base = (it * 1024 + tid) * 4;
        uint4 pv = *reinterpret_cast<const uint4*>(&hp2[base]);
        uint4 nv = *reinterpret_cast<const uint4*>(&hn2[base]);
        unsigned pa[4] = {pv.x, pv.y, pv.z, pv.w};
        unsigned na[4] = {nv.x, nv.y, nv.z, nv.w};
#pragma unroll
        for (int e = 0; e < 4; ++e) {
            float pd = decf(pa[e]);          // min dot over pos
            float nd = decf(na[e]);          // max dot over neg
            float hpv = sqrtf(fmaxf(2.0f - 2.0f * pd, 0.f));
            float hnv = sqrtf(fmaxf(2.0f - 2.0f * nd, 0.f));
            // relu(hp - hn + 0.5*(1+hp)) = relu(1.5*hp + 0.5 - hn)
            sum += fmaxf(fmaf(1.5f, hpv, 0.5f) - hnv, 0.f);
        }
    }
    __shared__ float red[1024];
    red[tid] = sum;
    __syncthreads();
    for (int s2 = 512; s2 > 0; s2 >>= 1) {
        if (tid < s2) red[tid] += red[tid + s2];
        __syncthreads();
    }
    if (tid == 0) out[0] = red[0] * (1.0f / (float)BN);    // all rows valid
}

// ---------------------------------------------------------------- launch
extern "C" void kernel_launch(void* const* d_in, const int* in_sizes, int n_in,
                              void* d_out, int out_size, void* d_ws, size_t ws_size,
                              hipStream_t stream) {
    const float* emb    = (const float*)d_in[0];
    const int*   labels = (const int*)d_in[1];
    float* out = (float*)d_out;

    char* ws = (char*)d_ws;
    unsigned short* ebf = (unsigned short*)ws;                            // 2 MiB sorted bf16 E
    int2*     se   = (int2*)    (ws + 2u * 1024u * 1024u);                // 64 KiB class ranges
    unsigned* hp2  = (unsigned*)(ws + 2u * 1024u * 1024u + 64u * 1024u);  // 32 KiB
    unsigned* hn2  = (unsigned*)(ws + 2u * 1024u * 1024u + 96u * 1024u);  // 32 KiB

    hipLaunchKernelGGL(sort_norm,       dim3(NCLS), dim3(256),  0, stream, emb, labels, ebf, se, hp2, hn2);
    hipLaunchKernelGGL(tri_main,        dim3(NBLK), dim3(256),  0, stream, ebf, se, hp2, hn2);
    hipLaunchKernelGGL(finalize_kernel, dim3(1),    dim3(1024), 0, stream, hp2, hn2, out);
}

// Round 17
// 45.300 us; speedup vs baseline: 1.3948x; 1.3662x over previous
//
#include <hip/hip_runtime.h>

#define BN   8192
#define DIM  128
#define NCLS 128
#define NBLK 1024         // 32 col-blocks (256 cols) x 32 i-splits (256 rows)
#define NSTR 4            // strips of 64 rows per block

typedef __attribute__((ext_vector_type(8))) short bf16x8;   // 8 x bf16 = 4 VGPRs
typedef __attribute__((ext_vector_type(8))) unsigned short u16x8;
typedef __attribute__((ext_vector_type(4))) float f32x4;

// round-to-nearest-even f32 -> bf16
static __device__ __forceinline__ unsigned short f2bf(float x) {
    union { float f; unsigned u; } c; c.f = x;
    unsigned r = c.u + 0x7FFFu + ((c.u >> 16) & 1u);
    return (unsigned short)(r >> 16);
}

static __device__ __forceinline__ bf16x8 ldb8(const unsigned short* p) {
    return *reinterpret_cast<const bf16x8*>(p);
}

// monotone float<->uint key: enc(a) < enc(b)  <=>  a < b
static __device__ __forceinline__ unsigned encf(float f) {
    unsigned u = __float_as_uint(f);
    return (u >> 31) ? ~u : (u | 0x80000000u);
}
static __device__ __forceinline__ float decf(unsigned v) {
    return __uint_as_float((v >> 31) ? (v & 0x7FFFFFFFu) : ~v);
}

// async global->LDS, 16B/lane; LDS dest wave-uniform base + lane*16
static __device__ __forceinline__ void gload_lds16(const unsigned short* g, unsigned short* l) {
    __builtin_amdgcn_global_load_lds(
        (const __attribute__((address_space(1))) unsigned int*)g,
        (__attribute__((address_space(3))) unsigned int*)l, 16, 0, 0);
}

// ---------------- S1: fused sort (block-per-class) + normalize + init -------
// R14 structure; normalize phase upgraded to 16-LANE ROW GROUPS: 16 rows in
// flight per block (was 4), 4 sequential iterations (was 16) -- the serial
// L2-load->reduce->store chain per row (~400cy) now overlaps 4x deeper.
__global__ __launch_bounds__(256) void sort_norm(const float* __restrict__ emb,
                                                 const int* __restrict__ labels,
                                                 unsigned short* __restrict__ ebf,
                                                 int2* __restrict__ se,
                                                 unsigned* __restrict__ hp2,
                                                 unsigned* __restrict__ hn2) {
    const int c   = blockIdx.x;              // class id
    const int tid = threadIdx.x;
    __shared__ int slab[BN];                 // 32 KiB label cache
    __shared__ int sl[256], so[256];
    __shared__ int srcrow[512];              // class size guard (E=64, sd~8)

#pragma unroll 8
    for (int k = 0; k < 32; ++k) {           // one coalesced label pass
        int idx = k * 256 + tid;
        slab[idx] = labels[idx];
    }
    __syncthreads();

    int nl = 0, no = 0;
#pragma unroll 8
    for (int k = 0; k < 32; ++k) {
        int lb = slab[k * 256 + tid];
        nl += (lb < c);
        no += (lb == c);
    }
    sl[tid] = nl; so[tid] = no;
    __syncthreads();
    for (int off = 1; off < 256; off <<= 1) {   // Hillis-Steele inclusive scan
        int a1 = 0, a2 = 0;
        if (tid >= off) { a1 = sl[tid - off]; a2 = so[tid - off]; }
        __syncthreads();
        sl[tid] += a1; so[tid] += a2;
        __syncthreads();
    }
    const int offs_c = sl[255];              // rows with label < c
    const int n_c    = so[255];              // class size
    int mypos = so[tid] - no;                // exclusive prefix of own-count
    for (int k = 0; k < 32; ++k) {           // deterministic placement
        int r = k * 256 + tid;
        if (slab[r] == c) srcrow[mypos++] = r;
    }
    __syncthreads();

    // ---- 16-lane-group normalize+scatter: lane holds 8 of 128 floats ----
    const int grp = tid >> 4;                // 0..15 (16 groups)
    const int gl  = tid & 15;                // lane within group
    for (int k = grp; k < n_c; k += 16) {
        const int r   = srcrow[k];
        const int pos = offs_c + k;
        const float4* rp = reinterpret_cast<const float4*>(emb + (size_t)r * DIM);
        float4 v0 = rp[gl * 2];
        float4 v1 = rp[gl * 2 + 1];
        float ss = v0.x * v0.x + v0.y * v0.y + v0.z * v0.z + v0.w * v0.w
                 + v1.x * v1.x + v1.y * v1.y + v1.z * v1.z + v1.w * v1.w;
#pragma unroll
        for (int m = 1; m < 16; m <<= 1) ss += __shfl_xor(ss, m);   // within group
        float inv = 1.0f / fmaxf(sqrtf(ss), 1e-12f);
        u16x8 bv;
        bv[0] = f2bf(v0.x * inv); bv[1] = f2bf(v0.y * inv);
        bv[2] = f2bf(v0.z * inv); bv[3] = f2bf(v0.w * inv);
        bv[4] = f2bf(v1.x * inv); bv[5] = f2bf(v1.y * inv);
        bv[6] = f2bf(v1.z * inv); bv[7] = f2bf(v1.w * inv);
        *reinterpret_cast<u16x8*>(ebf + (size_t)pos * DIM + gl * 8) = bv;
        if (gl == 0) {
            se[pos]  = make_int2(offs_c, offs_c + n_c);
            hp2[pos] = 0xFFFFFFFFu;          // min-key identity
            hn2[pos] = 0u;                   // max-key identity
        }
    }
}

// --------------------------------- main (byte-identical to measured-best R14)
// 1024 blocks = 32 col-blocks (256 cols) x 32 i-splits (256 rows, 4 strips).
// 64 cols/wave in regs (B=64 VGPR), LDS-staged A strips (double-buffered
// gload_lds + swizzle), hoisted pure-neg fast path. No fence, no done counter
// (R14: removing the per-block L2-flush storm was the big win).
__global__ __launch_bounds__(256) void tri_main(const unsigned short* __restrict__ ebf,
                                                const int2* __restrict__ se,
                                                unsigned* __restrict__ hp2,
                                                unsigned* __restrict__ hn2) {
    __shared__ alignas(16) unsigned short as_[2][64 * DIM];   // 2 x 16 KiB A strips

    const int tid  = threadIdx.x;
    const int wave = tid >> 6;
    const int lane = tid & 63;
    const int lr   = lane & 15;        // col within 16-subtile / A row in frag
    const int lk   = lane >> 4;        // k-group / C row-group
    const int jb   = blockIdx.x >> 5;  // col-block (256 cols)
    const int isp  = blockIdx.x & 31;  // i-split (256 rows)
    const int jc0  = jb * 256 + wave * 64;       // wave's col base (64 cols)
    const int rb0  = isp * 256;                  // block's row base

    // B fragments: 4 col-subtiles x 4 k-steps = 64 VGPRs, loaded once (L2-hit)
    bf16x8 b[4][4];
#pragma unroll
    for (int cs = 0; cs < 4; ++cs)
#pragma unroll
        for (int kk = 0; kk < 4; ++kk)
            b[cs][kk] = ldb8(ebf + (size_t)(jc0 + cs * 16 + lr) * DIM + kk * 32 + lk * 8);

    // lane's 4 columns' class ranges (loop-invariant)
    int qs[4], qe[4];
#pragma unroll
    for (int cs = 0; cs < 4; ++cs) {
        int2 q = se[jc0 + cs * 16 + lr];
        qs[cs] = q.x; qe[cs] = q.y;
    }

    float hp[4] = {1e30f, 1e30f, 1e30f, 1e30f};      // dot-space: min-pos
    float hn[4] = {-1e30f, -1e30f, -1e30f, -1e30f};  // dot-space: max-neg

    // A ds_read offsets: frag(t,kk) at byte (t*16+lr)*256 + perm[kk]
    int perm[4];
#pragma unroll
    for (int kk = 0; kk < 4; ++kk) perm[kk] = ((kk * 4 + lk) ^ (lr & 7)) << 4;

    // staging: wave stages rows [wave*16, wave*16+16) of the strip; source
    // chunk XOR'd by (row&7) so the linear LDS write realizes the swizzle
    const int rloc  = lane >> 4;             // row within 4-group
    const int chunk = lane & 15;             // physical 16B chunk
    auto STAGE = [&](int buf, int s) {
        const unsigned short* g0 = ebf + (size_t)(rb0 + s * 64) * DIM;
        unsigned short* lb = &as_[buf][wave * 16 * DIM];
#pragma unroll
        for (int l = 0; l < 4; ++l) {
            const int row = l * 4 + rloc;
            gload_lds16(g0 + (size_t)(wave * 16 + row) * DIM + ((chunk ^ (row & 7)) * 8),
                        lb + l * 4 * DIM);
        }
    };

    STAGE(0, 0);
    __syncthreads();

    for (int s = 0; s < NSTR; ++s) {
        if (s < NSTR - 1) STAGE((s + 1) & 1, s + 1);   // async prefetch next strip

        const char* bb = reinterpret_cast<const char*>(&as_[s & 1][0]);
        f32x4 acc[4][4];                     // [cs][t], unified VGPR/AGPR file
#pragma unroll
        for (int cs = 0; cs < 4; ++cs)
#pragma unroll
            for (int t = 0; t < 4; ++t) acc[cs][t] = f32x4{0.f, 0.f, 0.f, 0.f};

#pragma unroll
        for (int t = 0; t < 4; ++t)
#pragma unroll
            for (int kk = 0; kk < 4; ++kk) {
                bf16x8 af = *reinterpret_cast<const bf16x8*>(bb + (t * 16 + lr) * 256 + perm[kk]);
                acc[0][t] = __builtin_amdgcn_mfma_f32_16x16x32_bf16(af, b[0][kk], acc[0][t], 0, 0, 0);
                acc[1][t] = __builtin_amdgcn_mfma_f32_16x16x32_bf16(af, b[1][kk], acc[1][t], 0, 0, 0);
                acc[2][t] = __builtin_amdgcn_mfma_f32_16x16x32_bf16(af, b[2][kk], acc[2][t], 0, 0, 0);
                acc[3][t] = __builtin_amdgcn_mfma_f32_16x16x32_bf16(af, b[3][kk], acc[3][t], 0, 0, 0);
            }

        // epilogue: C layout col=lane&15, row=lk*4+m (+t*16)
        const int rb = rb0 + s * 64;
        bool mixed = false;
#pragma unroll
        for (int cs = 0; cs < 4; ++cs)
            mixed |= (qs[cs] < rb + 64) && (qe[cs] > rb);   // class range hits strip

        if (!__any(mixed)) {
            // pure-negative strip for every lane's columns: 1 fmax per element
#pragma unroll
            for (int cs = 0; cs < 4; ++cs) {
                float mx = hn[cs];
#pragma unroll
                for (int t = 0; t < 4; ++t)
#pragma unroll
                    for (int m = 0; m < 4; ++m) mx = fmaxf(mx, acc[cs][t][m]);
                hn[cs] = mx;
            }
        } else {                             // mixed strip (rare, near class band)
#pragma unroll
            for (int cs = 0; cs < 4; ++cs)
#pragma unroll
                for (int t = 0; t < 4; ++t)
#pragma unroll
                    for (int m = 0; m < 4; ++m) {
                        const int rowg = rb + t * 16 + lk * 4 + m;
                        const float d = acc[cs][t][m];
                        const bool pos = (rowg >= qs[cs]) && (rowg < qe[cs]);
                        hp[cs] = pos ? fminf(hp[cs], d) : hp[cs];
                        hn[cs] = pos ? hn[cs] : fmaxf(hn[cs], d);
                    }
        }

        __syncthreads();   // strip s reads done by all waves + strip s+1 landed
    }

    // combine the 4 lk-groups (lanes lr, lr+16, lr+32, lr+48 share columns)
#pragma unroll
    for (int cs = 0; cs < 4; ++cs) {
#pragma unroll
        for (int sft = 16; sft < 64; sft <<= 1) {
            hp[cs] = fminf(hp[cs], __shfl_xor(hp[cs], sft));
            hn[cs] = fmaxf(hn[cs], __shfl_xor(hn[cs], sft));
        }
    }
    if (lane < 16) {
#pragma unroll
        for (int cs = 0; cs < 4; ++cs) {
            atomicMin(&hp2[jc0 + cs * 16 + lane], encf(hp[cs]));
            atomicMax(&hn2[jc0 + cs * 16 + lane], encf(hn[cs]));
        }
    }
    // NO __threadfence, NO done counter: coherence from the kernel boundary.
}

// ---------------------------------------------------------------- finalize
__global__ __launch_bounds__(1024) void finalize_kernel(const unsigned* __restrict__ hp2,
                                                        const unsigned* __restrict__ hn2,
                                                        float* __restrict__ out) {
    const int tid = threadIdx.x;
    float sum = 0.f;
#pragma unroll
    for (int it = 0; it < BN / (1024 * 4); ++it) {   // 2 iters, uint4 per thread
        int base = (it * 1024 + tid) * 4;
        uint4 pv = *reinterpret_cast<const uint4*>(&hp2[base]);
        uint4 nv = *reinterpret_cast<const uint4*>(&hn2[base]);
        unsigned pa[4] = {pv.x, pv.y, pv.z, pv.w};
        unsigned na[4] = {nv.x, nv.y, nv.z, nv.w};
#pragma unroll
        for (int e = 0; e < 4; ++e) {
            float pd = decf(pa[e]);          // min dot over pos
            float nd = decf(na[e]);          // max dot over neg
            float hpv = sqrtf(fmaxf(2.0f - 2.0f * pd, 0.f));
            float hnv = sqrtf(fmaxf(2.0f - 2.0f * nd, 0.f));
            // relu(hp - hn + 0.5*(1+hp)) = relu(1.5*hp + 0.5 - hn)
            sum += fmaxf(fmaf(1.5f, hpv, 0.5f) - hnv, 0.f);
        }
    }
    __shared__ float red[1024];
    red[tid] = sum;
    __syncthreads();
    for (int s2 = 512; s2 > 0; s2 >>= 1) {
        if (tid < s2) red[tid] += red[tid + s2];
        __syncthreads();
    }
    if (tid == 0) out[0] = red[0] * (1.0f / (float)BN);    // all rows valid
}

// ---------------------------------------------------------------- launch
extern "C" void kernel_launch(void* const* d_in, const int* in_sizes, int n_in,
                              void* d_out, int out_size, void* d_ws, size_t ws_size,
                              hipStream_t stream) {
    const float* emb    = (const float*)d_in[0];
    const int*   labels = (const int*)d_in[1];
    float* out = (float*)d_out;

    char* ws = (char*)d_ws;
    unsigned short* ebf = (unsigned short*)ws;                            // 2 MiB sorted bf16 E
    int2*     se   = (int2*)    (ws + 2u * 1024u * 1024u);                // 64 KiB class ranges
    unsigned* hp2  = (unsigned*)(ws + 2u * 1024u * 1024u + 64u * 1024u);  // 32 KiB
    unsigned* hn2  = (unsigned*)(ws + 2u * 1024u * 1024u + 96u * 1024u);  // 32 KiB

    hipLaunchKernelGGL(sort_norm,       dim3(NCLS), dim3(256),  0, stream, emb, labels, ebf, se, hp2, hn2);
    hipLaunchKernelGGL(tri_main,        dim3(NBLK), dim3(256),  0, stream, ebf, se, hp2, hn2);
    hipLaunchKernelGGL(finalize_kernel, dim3(1),    dim3(1024), 0, stream, hp2, hn2, out);
}